// Round 7
// baseline (200.332 us; speedup 1.0000x reference)
//
#include <hip/hip_runtime.h>
#include <hip/hip_bf16.h>
#include <stdint.h>

#define BB     8
#define CC     320
#define NN     4096
#define SKV    77
#define HEADS  8
#define INNER  512
#define SCALE  0.125f

typedef float f32x4  __attribute__((ext_vector_type(4)));
typedef short bf16x8 __attribute__((ext_vector_type(8)));
typedef short s16x4  __attribute__((ext_vector_type(4)));

static __device__ __forceinline__ short f2bf(float f) {
  unsigned u = __float_as_uint(f);
  return (short)((u + 0x7fffu + ((u >> 16) & 1u)) >> 16);
}

// async global->LDS 16B copy; LDS dest is wave-uniform base + lane*16.
static __device__ __forceinline__ void gll16(void* lds, const void* g) {
  auto gp = reinterpret_cast<const uint32_t __attribute__((address_space(1)))*>(
      reinterpret_cast<uintptr_t>(g));
  auto lp = reinterpret_cast<uint32_t __attribute__((address_space(3)))*>(
      reinterpret_cast<uintptr_t>(lds));
  __builtin_amdgcn_global_load_lds(gp, lp, 16, 0, 0);
}

// ---------------------------------------------------------------------------
// prep: kv->bf16 | Wk,Wv,Wq(x SCALE),Wo tiled transposes | zero V_ws pad.
// blocks: [0,616) kv | [616,872) Wk/Wv | [872,912) Wq | [912,952) Wo |
// [952,1192) zero V_ws
// ---------------------------------------------------------------------------
__global__ __launch_bounds__(256) void prep_kernel(
    const float* __restrict__ kv, const float* __restrict__ Wk,
    const float* __restrict__ Wv, const float* __restrict__ Wq,
    const float* __restrict__ Wo, short* __restrict__ kv_bf,
    short* __restrict__ Wk_t, short* __restrict__ Wv_t,
    short* __restrict__ Wq_t, short* __restrict__ Wo_t,
    unsigned* __restrict__ zero_base) {
  __shared__ float T[64 * 65];
  const int blk = blockIdx.x, t = threadIdx.x;
  if (blk < 616) {
    const int base = blk * 1024;
    #pragma unroll
    for (int i = 0; i < 4; ++i) kv_bf[base + i*256 + t] = f2bf(kv[base + i*256 + t]);
    return;
  }
  if (blk >= 952) {              // zero V_ws (pad cols read by PV must be 0)
    const int base = (blk - 952) * 1024;
    #pragma unroll
    for (int i = 0; i < 4; ++i) zero_base[base + i*256 + t] = 0u;
    return;
  }
  const float* src; short* dst; int RS, CS, kt, ct; float scl = 1.0f;
  if (blk < 872) {               // Wk/Wv: [1024][512] -> [512][1024]
    const int tile = blk - 616;
    const bool isK = tile < 128;
    const int tt = isK ? tile : tile - 128;
    src = isK ? Wk : Wv; dst = isK ? Wk_t : Wv_t;
    RS = 1024; CS = 512; kt = tt >> 3; ct = tt & 7;
  } else if (blk < 912) {        // Wq: [320][512] -> [512][320], x SCALE
    const int tt = blk - 872;
    src = Wq; dst = Wq_t; RS = 320; CS = 512; kt = tt >> 3; ct = tt & 7;
    scl = SCALE;
  } else {                       // Wo: [512][320] -> [320][512]
    const int tt = blk - 912;
    src = Wo; dst = Wo_t; RS = 512; CS = 320; kt = tt / 5; ct = tt % 5;
  }
  const int cl = t & 63, rb = t >> 6;
  #pragma unroll
  for (int i = 0; i < 16; ++i)
    T[(rb + i*4)*65 + cl] = src[(size_t)(kt*64 + rb + i*4)*CS + ct*64 + cl];
  __syncthreads();
  #pragma unroll
  for (int i = 0; i < 16; ++i) {
    const int nl = rb + i*4;
    dst[(size_t)(ct*64 + nl)*RS + kt*64 + cl] = f2bf(T[cl*65 + nl] * scl);
  }
}

// ---------------------------------------------------------------------------
// kvproj v2: K-split across 4 waves (256k each) + LDS atomic reduce.
// grid (10,16): 10 m-tiles of 64 rows x (isK, h). Per-block critical path:
// 8 K-steps (was 32), then 64x64 f32 reduction in LDS.
// ---------------------------------------------------------------------------
__global__ __launch_bounds__(256) void kvproj_kernel(
    const short* __restrict__ kv_bf, const short* __restrict__ Wk_t,
    const short* __restrict__ Wv_t, short* __restrict__ K_ws,
    short* __restrict__ V_ws) {
  const int t = threadIdx.x, w = t >> 6, lane = t & 63;
  const int l15 = lane & 15, q = lane >> 4;
  const int m0 = blockIdx.x * 64;
  const int y = blockIdx.y;
  const bool isK = (y < 8);
  const int h = y & 7;
  const short* __restrict__ Wt = isK ? Wk_t : Wv_t;

  __shared__ float buf[4096];
  for (int i = t; i < 4096; i += 256) buf[i] = 0.f;
  __syncthreads();

  const f32x4 z = {0.f, 0.f, 0.f, 0.f};
  f32x4 acc[4][4];
  #pragma unroll
  for (int ms = 0; ms < 4; ++ms)
    #pragma unroll
    for (int nt = 0; nt < 4; ++nt) acc[ms][nt] = z;

  const int kbase = w * 256;
  for (int kk = 0; kk < 256; kk += 32) {
    const int k0 = kbase + kk;
    bf16x8 a[4];
    #pragma unroll
    for (int ms = 0; ms < 4; ++ms) {
      int arow = m0 + ms*16 + l15;
      if (arow > 615) arow = 615;
      a[ms] = *(const bf16x8*)(kv_bf + (size_t)arow*1024 + k0 + q*8);
    }
    #pragma unroll
    for (int nt = 0; nt < 4; ++nt) {
      const int n = h*64 + nt*16 + l15;
      const bf16x8 bfr = *(const bf16x8*)(Wt + (size_t)n*1024 + k0 + q*8);
      #pragma unroll
      for (int ms = 0; ms < 4; ++ms)
        acc[ms][nt] = __builtin_amdgcn_mfma_f32_16x16x32_bf16(a[ms], bfr, acc[ms][nt], 0, 0, 0);
    }
  }
  #pragma unroll
  for (int ms = 0; ms < 4; ++ms)
    #pragma unroll
    for (int nt = 0; nt < 4; ++nt)
      #pragma unroll
      for (int r = 0; r < 4; ++r)
        atomicAdd(&buf[(ms*16 + q*4 + r)*64 + nt*16 + l15], acc[ms][nt][r]);
  __syncthreads();
  for (int i = t; i < 4096; i += 256) {
    const int m = i >> 6, d = i & 63;
    const int row = m0 + m;
    if (row < 616) {
      const int b = (int)(((unsigned)row * 54472u) >> 22);   // row/77
      const int s = row - b*77;
      if (isK) K_ws[((b*8 + h)*80 + s)*64 + d] = f2bf(buf[i]);
      else     V_ws[((b*8 + h)*64 + d)*96 + s] = f2bf(buf[i]);
    }
  }
}

// ---------------------------------------------------------------------------
// qproj: Q[64tok x 512j] per block; grid 512 (8b x 64 n-tiles) = 2 blocks/CU.
// Phase 0: query fp32 -> A[64][328] bf16 in-LDS transpose (no X_bf pass).
// Phase 1: wave w owns j [128w,128w+128); wave-private half-staging of Wq
// rows via gll16 (256 slots/half, XOR swizzle perm(r)=(r&3)^((r>>2)&3) ->
// 2-way bank = free), counted vmcnt, no block barriers in K-loop.
// LDS: A 41,984 B + 4 x 4,096 B slices = 58,368 B -> 2 blocks/CU.
// ---------------------------------------------------------------------------
__global__ __launch_bounds__(256, 2) void qproj_kernel(
    const float* __restrict__ query, const short* __restrict__ Wq_t,
    short* __restrict__ Q_ws) {
  const int t = threadIdx.x, w = t >> 6, lane = t & 63;
  const int l15 = lane & 15, q = lane >> 4;
  const int b = blockIdx.x >> 6;
  const int n0 = (blockIdx.x & 63) * 64;

  __shared__ short S[29184];           // A[64][328] @0 | slices @20992
  short* slice = S + 20992 + w * 2048;

  // phase 0: query -> A[tok][c]
  {
    const float* qb = query + (size_t)b * CC * NN + n0;
    #pragma unroll
    for (int i = 0; i < 20; ++i) {
      const int f = i * 256 + t;
      const int c = f >> 4, n4 = (f & 15) * 4;
      const f32x4 v = *(const f32x4*)(qb + (size_t)c * NN + n4);
      #pragma unroll
      for (int j = 0; j < 4; ++j)
        S[(n4 + j) * 328 + c] = f2bf(v[j]);
    }
  }

  f32x4 acc[4][8];
  const f32x4 z = {0.f, 0.f, 0.f, 0.f};
  #pragma unroll
  for (int mt = 0; mt < 4; ++mt)
    #pragma unroll
    for (int nt = 0; nt < 8; ++nt) acc[mt][nt] = z;

  const short* __restrict__ Wqw = Wq_t + (size_t)(w * 128) * 320;
  auto stage = [&](int it, int h2) {     // 64 rows x 32k = 256 slots
    const int k0 = it * 32;
    #pragma unroll
    for (int p = 0; p < 4; ++p) {
      const int L = p * 64 + lane;
      const int row = L >> 2, qp = L & 3;
      const int ql = qp ^ ((row & 3) ^ ((row >> 2) & 3));
      gll16(slice + L * 8, Wqw + (size_t)(h2 * 64 + row) * 320 + k0 + ql * 8);
    }
  };

  stage(0, 0);
  __syncthreads();   // A-panel ready
  const int lperm = (l15 & 3) ^ ((l15 >> 2) & 3);
  for (int it = 0; it < 10; ++it) {
    const int k0 = it * 32;
    asm volatile("s_waitcnt vmcnt(0)" ::: "memory");   // half-0 staged
    __builtin_amdgcn_sched_barrier(0);
    bf16x8 a[4], b0[4];
    #pragma unroll
    for (int mt = 0; mt < 4; ++mt)
      a[mt] = *(const bf16x8*)(S + (mt * 16 + l15) * 328 + k0 + q * 8);
    #pragma unroll
    for (int x = 0; x < 4; ++x) {
      const int r = x * 16 + l15;
      b0[x] = *(const bf16x8*)(slice + (r * 4 + (q ^ lperm)) * 8);
    }
    asm volatile("s_waitcnt lgkmcnt(0)" ::: "memory");
    __builtin_amdgcn_sched_barrier(0);
    stage(it, 1);
    #pragma unroll
    for (int mt = 0; mt < 4; ++mt)
      #pragma unroll
      for (int x = 0; x < 4; ++x)
        acc[mt][x] = __builtin_amdgcn_mfma_f32_16x16x32_bf16(a[mt], b0[x], acc[mt][x], 0, 0, 0);

    asm volatile("s_waitcnt vmcnt(0)" ::: "memory");   // half-1 staged
    __builtin_amdgcn_sched_barrier(0);
    bf16x8 b1[4];
    #pragma unroll
    for (int x = 0; x < 4; ++x) {
      const int r = x * 16 + l15;
      b1[x] = *(const bf16x8*)(slice + (r * 4 + (q ^ lperm)) * 8);
    }
    asm volatile("s_waitcnt lgkmcnt(0)" ::: "memory");
    __builtin_amdgcn_sched_barrier(0);
    if (it + 1 < 10) stage(it + 1, 0);
    #pragma unroll
    for (int mt = 0; mt < 4; ++mt)
      #pragma unroll
      for (int x = 0; x < 4; ++x)
        acc[mt][4 + x] = __builtin_amdgcn_mfma_f32_16x16x32_bf16(a[mt], b1[x], acc[mt][4 + x], 0, 0, 0);
  }
  #pragma unroll
  for (int mt = 0; mt < 4; ++mt)
    #pragma unroll
    for (int r = 0; r < 4; ++r) {
      const int tok = n0 + mt * 16 + q * 4 + r;
      short* rowp = Q_ws + (size_t)(b * NN + tok) * 512 + w * 128;
      #pragma unroll
      for (int nt = 0; nt < 8; ++nt)
        rowp[nt * 16 + l15] = f2bf(acc[mt][nt][r]);
    }
}

// ---------------------------------------------------------------------------
// attncore: 4 waves/block; each wave = 32 tokens (2 n-tiles) x 1 head,
// fully independent. Q pre-scaled by 0.125 (folded into Wq_t).
// QK^T -> shfl softmax x2 -> P via per-wave LDS -> PV -> O_ws.
// 8192 independent wave-units. (round-0 proven kernel)
// ---------------------------------------------------------------------------
__global__ __launch_bounds__(256) void attncore_kernel(
    const short* __restrict__ Q_ws, const short* __restrict__ K_ws,
    const short* __restrict__ V_ws, short* __restrict__ O_ws) {
  const int t = threadIdx.x, w = t >> 6, lane = t & 63;
  const int unit = blockIdx.x * 4 + w;
  const int h = unit & 7;
  const int g = unit >> 3;                 // 32-token tile 0..1023
  const int b = g >> 7;
  const int n0 = (g & 127) * 32;
  const int l15 = lane & 15, q = lane >> 4;

  __shared__ short scr[4 * 32 * 104];      // per-wave P scratch
  short* scrw = scr + w * 32 * 104;
  for (int i = lane; i < 32*104/2; i += 64) ((unsigned*)scrw)[i] = 0u;

  const short* __restrict__ Kh = K_ws + (size_t)(b*8 + h) * 80 * 64;
  const short* __restrict__ Vh = V_ws + (size_t)(b*8 + h) * 64 * 96;
  size_t tokrow[2];
  #pragma unroll
  for (int nt = 0; nt < 2; ++nt) tokrow[nt] = (size_t)(b*NN + n0 + nt*16 + l15);

  const f32x4 z = {0.f, 0.f, 0.f, 0.f};
  f32x4 qk[2][5];
  #pragma unroll
  for (int nt = 0; nt < 2; ++nt)
    #pragma unroll
    for (int st = 0; st < 5; ++st) qk[nt][st] = z;
  #pragma unroll
  for (int f = 0; f < 2; ++f) {
    bf16x8 bq[2];
    #pragma unroll
    for (int nt = 0; nt < 2; ++nt)
      bq[nt] = *(const bf16x8*)(Q_ws + tokrow[nt]*512 + h*64 + f*32 + q*8);
    #pragma unroll
    for (int st = 0; st < 5; ++st) {
      const bf16x8 a = *(const bf16x8*)(Kh + (st*16 + l15)*64 + f*32 + q*8);
      #pragma unroll
      for (int nt = 0; nt < 2; ++nt)
        qk[nt][st] = __builtin_amdgcn_mfma_f32_16x16x32_bf16(a, bq[nt], qk[nt][st], 0, 0, 0);
    }
  }

  #pragma unroll
  for (int nt = 0; nt < 2; ++nt) {
    float mx = -1e30f;
    #pragma unroll
    for (int st = 0; st < 5; ++st)
      #pragma unroll
      for (int r = 0; r < 4; ++r) {
        const int s = st*16 + q*4 + r;
        const float vv = (s < SKV) ? qk[nt][st][r] : -1e30f;
        qk[nt][st][r] = vv;
        mx = fmaxf(mx, vv);
      }
    mx = fmaxf(mx, __shfl_xor(mx, 16));
    mx = fmaxf(mx, __shfl_xor(mx, 32));
    float sum = 0.f;
    #pragma unroll
    for (int st = 0; st < 5; ++st)
      #pragma unroll
      for (int r = 0; r < 4; ++r) {
        const int s = st*16 + q*4 + r;
        const float e = (s < SKV) ? __expf(qk[nt][st][r] - mx) : 0.f;
        qk[nt][st][r] = e;
        sum += e;
      }
    sum += __shfl_xor(sum, 16);
    sum += __shfl_xor(sum, 32);
    const float inv = 1.0f / sum;
    #pragma unroll
    for (int st = 0; st < 5; ++st) {
      s16x4 pv;
      #pragma unroll
      for (int r = 0; r < 4; ++r) pv[r] = f2bf(qk[nt][st][r] * inv);
      *(s16x4*)(scrw + (nt*16 + l15)*104 + st*16 + q*4) = pv;
    }
  }

  f32x4 ov[2][4];
  #pragma unroll
  for (int nt = 0; nt < 2; ++nt)
    #pragma unroll
    for (int dt = 0; dt < 4; ++dt) ov[nt][dt] = z;
  #pragma unroll
  for (int f = 0; f < 3; ++f) {
    bf16x8 bp[2];
    #pragma unroll
    for (int nt = 0; nt < 2; ++nt)
      bp[nt] = *(const bf16x8*)(scrw + (nt*16 + l15)*104 + f*32 + q*8);
    #pragma unroll
    for (int dt = 0; dt < 4; ++dt) {
      const bf16x8 a = *(const bf16x8*)(Vh + (dt*16 + l15)*96 + f*32 + q*8);
      #pragma unroll
      for (int nt = 0; nt < 2; ++nt)
        ov[nt][dt] = __builtin_amdgcn_mfma_f32_16x16x32_bf16(a, bp[nt], ov[nt][dt], 0, 0, 0);
    }
  }
  #pragma unroll
  for (int nt = 0; nt < 2; ++nt)
    #pragma unroll
    for (int dt = 0; dt < 4; ++dt) {
      s16x4 pv;
      #pragma unroll
      for (int r = 0; r < 4; ++r) pv[r] = f2bf(ov[nt][dt][r]);
      *(s16x4*)(O_ws + tokrow[nt]*512 + h*64 + dt*16 + q*4) = pv;
    }
}

// ---------------------------------------------------------------------------
// outproj: out^T = Wo_t[320][512] @ O_ws^T -> out[b][c][n] + bias.
// m97-style: A=Wo_t BM=160, B=O_ws BN=128 tok, BK=32; wave = 5m x 4n.
// grid 512 blocks. Coalesced fp32 epilogue. (round-0 proven kernel)
// ---------------------------------------------------------------------------
__global__ __launch_bounds__(256) void outproj_kernel(
    const short* __restrict__ O_ws, const short* __restrict__ Wo_t,
    const float* __restrict__ bo, float* __restrict__ out) {
  const int t = threadIdx.x, w = t >> 6, lane = t & 63;
  const int l15 = lane & 15, q = lane >> 4;
  const int c0 = (blockIdx.x & 1) * 160;
  const int t0 = (blockIdx.x >> 1) * 128;
  const int wm = w & 1, wn = w >> 1;

  __shared__ short tile[9216];   // A[160][32] @0 (5120 sh), B[128][32] @5120

  const f32x4 z = {0.f, 0.f, 0.f, 0.f};
  f32x4 acc[5][4];
  #pragma unroll
  for (int mt = 0; mt < 5; ++mt)
    #pragma unroll
    for (int nt = 0; nt < 4; ++nt) acc[mt][nt] = z;

  for (int it = 0; it < 16; ++it) {
    const int k0 = it * 32;
    if (it) __syncthreads();
    #pragma unroll
    for (int p = 0; p < 5; ++p) {
      const int f = p*256 + t;
      if (f < 1152) {
        const short* g;
        if (f < 640) {
          const int row = f >> 2, c4 = f & 3;
          g = Wo_t + (size_t)(c0 + row)*512 + k0 + c4*8;
        } else {
          const int f2 = f - 640, row = f2 >> 2, c4 = f2 & 3;
          g = O_ws + (size_t)(t0 + row)*512 + k0 + c4*8;
        }
        gll16(tile + f*8, g);
      }
    }
    __syncthreads();
    bf16x8 a[5], bb[4];
    #pragma unroll
    for (int mt = 0; mt < 5; ++mt)
      a[mt] = *(const bf16x8*)(tile + (wm*80 + mt*16 + l15)*32 + q*8);
    #pragma unroll
    for (int nt = 0; nt < 4; ++nt)
      bb[nt] = *(const bf16x8*)(tile + 5120 + (wn*64 + nt*16 + l15)*32 + q*8);
    #pragma unroll
    for (int mt = 0; mt < 5; ++mt)
      #pragma unroll
      for (int nt = 0; nt < 4; ++nt)
        acc[mt][nt] = __builtin_amdgcn_mfma_f32_16x16x32_bf16(a[mt], bb[nt], acc[mt][nt], 0, 0, 0);
  }
  const int b = t0 >> 12, n = t0 & 4095;
  #pragma unroll
  for (int mt = 0; mt < 5; ++mt)
    #pragma unroll
    for (int r = 0; r < 4; ++r) {
      const int c = c0 + wm*80 + mt*16 + q*4 + r;
      const float bv = bo[c];
      float* rowp = out + ((size_t)(b*CC + c))*NN + n + wn*64;
      #pragma unroll
      for (int nt = 0; nt < 4; ++nt)
        rowp[nt*16 + l15] = acc[mt][nt][r] + bv;
    }
}

// ---------------------------------------------------------------------------
extern "C" void kernel_launch(void* const* d_in, const int* in_sizes, int n_in,
                              void* d_out, int out_size, void* d_ws, size_t ws_size,
                              hipStream_t stream) {
  const float* query = (const float*)d_in[0];
  const float* kv    = (const float*)d_in[1];
  const float* Wq    = (const float*)d_in[2];
  const float* Wk    = (const float*)d_in[3];
  const float* Wv    = (const float*)d_in[4];
  const float* Wo    = (const float*)d_in[5];
  const float* bo    = (const float*)d_in[6];
  float* out = (float*)d_out;

  char* p = (char*)d_ws;
  short* K_ws  = (short*)(p);             //   819,200 B [8][8][80][64]
  short* V_ws  = (short*)(p +   819200);  //   983,040 B [8][8][64][96]
  short* Wq_t  = (short*)(p +  1802240);  //   327,680 B [512][320] (x SCALE)
  short* Wo_t  = (short*)(p +  2129920);  //   327,680 B [320][512]
  short* kv_bf = (short*)(p +  2457600);  //  1,261,568 B [616][1024]
  short* Wk_t  = (short*)(p +  3719168);  //  1,048,576 B [512][1024]
  short* Wv_t  = (short*)(p +  4767744);  //  1,048,576 B [512][1024]
  short* Q_ws  = (short*)(p +  5816320);  // 33,554,432 B [32768][512]
  short* O_ws  = (short*)(p + 39370752);  // 33,554,432 B [32768][512]

  prep_kernel<<<1192, 256, 0, stream>>>(kv, Wk, Wv, Wq, Wo, kv_bf,
                                        Wk_t, Wv_t, Wq_t, Wo_t,
                                        (unsigned*)V_ws);
  kvproj_kernel<<<dim3(10, 16), 256, 0, stream>>>(kv_bf, Wk_t, Wv_t, K_ws, V_ws);
  qproj_kernel<<<512, 256, 0, stream>>>(query, Wq_t, Q_ws);
  attncore_kernel<<<2048, 256, 0, stream>>>(Q_ws, K_ws, V_ws, O_ws);
  outproj_kernel<<<512, 256, 0, stream>>>(O_ws, Wo_t, bo, out);
}

// Round 8
// 185.346 us; speedup vs baseline: 1.0809x; 1.0809x over previous
//
#include <hip/hip_runtime.h>
#include <hip/hip_bf16.h>
#include <stdint.h>

#define BB     8
#define CC     320
#define NN     4096
#define SKV    77
#define HEADS  8
#define INNER  512
#define SCALE  0.125f

typedef float f32x4  __attribute__((ext_vector_type(4)));
typedef short bf16x8 __attribute__((ext_vector_type(8)));
typedef short s16x4  __attribute__((ext_vector_type(4)));

static __device__ __forceinline__ short f2bf(float f) {
  unsigned u = __float_as_uint(f);
  return (short)((u + 0x7fffu + ((u >> 16) & 1u)) >> 16);
}

// async global->LDS 16B copy; LDS dest is wave-uniform base + lane*16.
static __device__ __forceinline__ void gll16(void* lds, const void* g) {
  auto gp = reinterpret_cast<const uint32_t __attribute__((address_space(1)))*>(
      reinterpret_cast<uintptr_t>(g));
  auto lp = reinterpret_cast<uint32_t __attribute__((address_space(3)))*>(
      reinterpret_cast<uintptr_t>(lds));
  __builtin_amdgcn_global_load_lds(gp, lp, 16, 0, 0);
}

// ---------------------------------------------------------------------------
// prep: kv->bf16 | Wk,Wv,Wq(x SCALE),Wo transposes | zero V_ws | query->X_bf.
// blocks: [0,616) kv | [616,872) Wk/Wv | [872,912) Wq | [912,952) Wo |
// [952,1208) zero V_ws (1 MB) | [1208,3768) xpose
// ---------------------------------------------------------------------------
__global__ __launch_bounds__(256) void prep_kernel(
    const float* __restrict__ kv, const float* __restrict__ Wk,
    const float* __restrict__ Wv, const float* __restrict__ Wq,
    const float* __restrict__ Wo, const float* __restrict__ query,
    short* __restrict__ kv_bf, short* __restrict__ Wk_t,
    short* __restrict__ Wv_t, short* __restrict__ Wq_t,
    short* __restrict__ Wo_t, short* __restrict__ X_bf,
    unsigned* __restrict__ zero_base) {
  __shared__ float T[64 * 65];
  const int blk = blockIdx.x, t = threadIdx.x;
  if (blk < 616) {
    const int base = blk * 1024;
    #pragma unroll
    for (int i = 0; i < 4; ++i) kv_bf[base + i*256 + t] = f2bf(kv[base + i*256 + t]);
    return;
  }
  if (blk >= 1208) {              // xpose: query [b][c][n] -> X_bf [b*N+n][320]
    const int blk2 = blk - 1208;
    const int b = blk2 / 320, r = blk2 % 320;
    const int nt = r / 5, ct = r % 5;
    const int tl = t & 63, rb = t >> 6;
    #pragma unroll
    for (int i = 0; i < 16; ++i) {
      const int c = rb + i*4;
      T[c*65 + tl] = query[((size_t)(b*CC + ct*64 + c))*NN + nt*64 + tl];
    }
    __syncthreads();
    #pragma unroll
    for (int i = 0; i < 16; ++i) {
      const int n = rb + i*4;
      X_bf[((size_t)(b*NN + nt*64 + n))*CC + ct*64 + tl] = f2bf(T[tl*65 + n]);
    }
    return;
  }
  if (blk >= 952) {               // zero V_ws (pad cols read by PV must be 0)
    const int base = (blk - 952) * 1024;
    #pragma unroll
    for (int i = 0; i < 4; ++i) zero_base[base + i*256 + t] = 0u;
    return;
  }
  const float* src; short* dst; int RS, CS, kt, ct; float scl = 1.0f;
  if (blk < 872) {               // Wk/Wv: [1024][512] -> [512][1024]
    const int tile = blk - 616;
    const bool isK = tile < 128;
    const int tt = isK ? tile : tile - 128;
    src = isK ? Wk : Wv; dst = isK ? Wk_t : Wv_t;
    RS = 1024; CS = 512; kt = tt >> 3; ct = tt & 7;
  } else if (blk < 912) {        // Wq: [320][512] -> [512][320], x SCALE
    const int tt = blk - 872;
    src = Wq; dst = Wq_t; RS = 320; CS = 512; kt = tt >> 3; ct = tt & 7;
    scl = SCALE;
  } else {                       // Wo: [512][320] -> [320][512]
    const int tt = blk - 912;
    src = Wo; dst = Wo_t; RS = 512; CS = 320; kt = tt / 5; ct = tt % 5;
  }
  const int cl = t & 63, rb = t >> 6;
  #pragma unroll
  for (int i = 0; i < 16; ++i)
    T[(rb + i*4)*65 + cl] = src[(size_t)(kt*64 + rb + i*4)*CS + ct*64 + cl];
  __syncthreads();
  #pragma unroll
  for (int i = 0; i < 16; ++i) {
    const int nl = rb + i*4;
    dst[(size_t)(ct*64 + nl)*RS + kt*64 + cl] = f2bf(T[cl*65 + nl] * scl);
  }
}

// ---------------------------------------------------------------------------
// kvproj (round-0 v1 structure): kv_bf @ Wk_t/Wv_t ->
// K_ws [b][h][80][64] (16B units XOR-swizzled: u ^= s&7)
// V_ws [b][h][64][128] (padded, units XOR-swizzled: u ^= d&15)
// ---------------------------------------------------------------------------
__global__ __launch_bounds__(256) void kvproj_kernel(
    const short* __restrict__ kv_bf, const short* __restrict__ Wk_t,
    const short* __restrict__ Wv_t, short* __restrict__ K_ws,
    short* __restrict__ V_ws) {
  const int t = threadIdx.x, w = t >> 6, lane = t & 63;
  const int l15 = lane & 15, q = lane >> 4;
  const int m0 = (blockIdx.x * 4 + w) * 16;
  const int y = blockIdx.y;
  const bool isK = (y < 8);
  const int h = y & 7;
  const short* __restrict__ Wt = isK ? Wk_t : Wv_t;
  const int arow = (m0 + l15 < 616) ? (m0 + l15) : 615;

  const f32x4 z = {0.f, 0.f, 0.f, 0.f};
  f32x4 acc[4] = {z, z, z, z};
  for (int k0 = 0; k0 < 1024; k0 += 32) {
    const bf16x8 a = *(const bf16x8*)(kv_bf + (size_t)arow*1024 + k0 + q*8);
    #pragma unroll
    for (int nt = 0; nt < 4; ++nt) {
      const int n = h*64 + nt*16 + l15;
      const bf16x8 bfr = *(const bf16x8*)(Wt + (size_t)n*1024 + k0 + q*8);
      acc[nt] = __builtin_amdgcn_mfma_f32_16x16x32_bf16(a, bfr, acc[nt], 0, 0, 0);
    }
  }
  #pragma unroll
  for (int nt = 0; nt < 4; ++nt) {
    const int d = nt*16 + l15;
    #pragma unroll
    for (int r = 0; r < 4; ++r) {
      const int row = m0 + q*4 + r;
      if (row < 616) {
        const int b = (int)(((unsigned)row * 54472u) >> 22);   // row/77
        const int s = row - b*77;
        if (isK) {
          const int u = (d >> 3) ^ (s & 7);
          K_ws[(size_t)((b*8 + h)*80 + s)*64 + u*8 + (d & 7)] = f2bf(acc[nt][r]);
        } else {
          const int u = (s >> 3) ^ (d & 15);
          V_ws[(size_t)((b*8 + h)*64 + d)*128 + u*8 + (s & 7)] = f2bf(acc[nt][r]);
        }
      }
    }
  }
}

// ---------------------------------------------------------------------------
// qproj v3: X_bf[32768][320] @ Wq_t[512][320] -> Q_ws[32768][512] bf16.
// BM=128, BN=256, BK=32, grid 512. 2-phase double-buffered staging (T3-min):
// issue stage(t+1) BEFORE compute(t); one barrier per K-step; XOR-swizzled
// staging units (u ^= (row&3)^((row>>2)&3)) kill the [row][32] conflicts.
// LDS 49,152 B -> 3 blocks/CU by LDS (VGPR-capped ~2).
// ---------------------------------------------------------------------------
__global__ __launch_bounds__(256, 2) void qproj_kernel(
    const short* __restrict__ X_bf, const short* __restrict__ Wq_t,
    short* __restrict__ Q_ws) {
  const int t = threadIdx.x, w = t >> 6, lane = t & 63;
  const int l15 = lane & 15, q = lane >> 4;
  const int m0 = (blockIdx.x >> 1) * 128;
  const int n0 = (blockIdx.x & 1) * 256;
  const int wm = w & 1, wn = w >> 1;

  __shared__ short tile[2][12288];   // per buf: A[128][32] @0, B[256][32] @4096

  auto stage = [&](int it, int bufi) {
    short* buf = tile[bufi];
    const int k0 = it * 32;
    #pragma unroll
    for (int p = 0; p < 2; ++p) {
      const int f = p*256 + t, row = f >> 2, c4 = f & 3;
      const int c4s = c4 ^ ((row & 3) ^ ((row >> 2) & 3));
      gll16(buf + f*8, X_bf + (size_t)(m0 + row)*320 + k0 + c4s*8);
    }
    #pragma unroll
    for (int p = 0; p < 4; ++p) {
      const int f = p*256 + t, row = f >> 2, c4 = f & 3;
      const int c4s = c4 ^ ((row & 3) ^ ((row >> 2) & 3));
      gll16(buf + 4096 + f*8, Wq_t + (size_t)(n0 + row)*320 + k0 + c4s*8);
    }
  };

  const f32x4 z = {0.f, 0.f, 0.f, 0.f};
  f32x4 acc[4][8];
  #pragma unroll
  for (int mt = 0; mt < 4; ++mt)
    #pragma unroll
    for (int nt = 0; nt < 8; ++nt) acc[mt][nt] = z;

  stage(0, 0);
  __syncthreads();                       // drains stage(0)
  const int lperm = (l15 & 3) ^ ((l15 >> 2) & 3);
  for (int it = 0; it < 10; ++it) {
    if (it + 1 < 10) stage(it + 1, (it + 1) & 1);   // in-flight across compute
    const short* buf = tile[it & 1];
    bf16x8 a[4], bb[8];
    #pragma unroll
    for (int mt = 0; mt < 4; ++mt)
      a[mt] = *(const bf16x8*)(buf + (wm*64 + mt*16 + l15)*32 + (q ^ lperm)*8);
    #pragma unroll
    for (int nt = 0; nt < 8; ++nt)
      bb[nt] = *(const bf16x8*)(buf + 4096 + (wn*128 + nt*16 + l15)*32 + (q ^ lperm)*8);
    #pragma unroll
    for (int mt = 0; mt < 4; ++mt)
      #pragma unroll
      for (int nt = 0; nt < 8; ++nt)
        acc[mt][nt] = __builtin_amdgcn_mfma_f32_16x16x32_bf16(a[mt], bb[nt], acc[mt][nt], 0, 0, 0);
    if (it + 1 < 10) __syncthreads();    // implicit vmcnt(0): stage(it+1) done
  }
  #pragma unroll
  for (int mt = 0; mt < 4; ++mt)
    #pragma unroll
    for (int r = 0; r < 4; ++r) {
      short* rowp = Q_ws + (size_t)(m0 + wm*64 + mt*16 + q*4 + r)*512 + n0 + wn*128;
      #pragma unroll
      for (int nt = 0; nt < 8; ++nt)
        rowp[nt*16 + l15] = f2bf(acc[mt][nt][r]);
    }
}

// ---------------------------------------------------------------------------
// attncore v2: block = (b, h, 256 tokens); 4 waves x 64 tok (2x 32-chunks).
// K/V staged ONCE per block via linear gll16 (global layout pre-swizzled by
// kvproj) -> all inner reads are conflict-free ds_read; zero global gathers
// for K/V. Q gathered from Q_ws (8 loads/chunk). grid 1024, LDS 53,248 B
// -> 3 blocks/CU.
// ---------------------------------------------------------------------------
__global__ __launch_bounds__(256) void attncore_kernel(
    const short* __restrict__ Q_ws, const short* __restrict__ K_ws,
    const short* __restrict__ V_ws, short* __restrict__ O_ws) {
  const int t = threadIdx.x, w = t >> 6, lane = t & 63;
  const int l15 = lane & 15, q = lane >> 4;
  const int b = blockIdx.x >> 7;
  const int r7 = blockIdx.x & 127;
  const int h = r7 >> 4;
  const int rng = r7 & 15;

  __shared__ short KL[80 * 64];        // swizzled units (u ^ (s&7))
  __shared__ short VL[64 * 128];       // swizzled units (u ^ (d&15))
  __shared__ short scr[4 * 32 * 104];  // per-wave P

  const short* __restrict__ Kg = K_ws + (size_t)(b*8 + h) * 80 * 64;
  const short* __restrict__ Vg = V_ws + (size_t)(b*8 + h) * 64 * 128;
  #pragma unroll
  for (int p = 0; p < 3; ++p) {
    const int L = p*256 + t;
    if (L < 640) gll16(KL + L*8, Kg + L*8);
  }
  #pragma unroll
  for (int p = 0; p < 4; ++p) {
    const int L = p*256 + t;
    gll16(VL + L*8, Vg + L*8);
  }
  short* scrw = scr + w * 3328;
  for (int i = lane; i < 1664; i += 64) ((unsigned*)scrw)[i] = 0u;
  __syncthreads();                     // K/V staged (implicit vmcnt drain)

  const f32x4 z = {0.f, 0.f, 0.f, 0.f};
  for (int chunk = 0; chunk < 2; ++chunk) {
    const int n0 = rng * 256 + w * 64 + chunk * 32;
    size_t tokrow[2];
    #pragma unroll
    for (int nt = 0; nt < 2; ++nt) tokrow[nt] = (size_t)(b*NN + n0 + nt*16 + l15);

    f32x4 qk[2][5];
    #pragma unroll
    for (int nt = 0; nt < 2; ++nt)
      #pragma unroll
      for (int st = 0; st < 5; ++st) qk[nt][st] = z;
    #pragma unroll
    for (int f = 0; f < 2; ++f) {
      bf16x8 bq[2];
      #pragma unroll
      for (int nt = 0; nt < 2; ++nt)
        bq[nt] = *(const bf16x8*)(Q_ws + tokrow[nt]*512 + h*64 + f*32 + q*8);
      #pragma unroll
      for (int st = 0; st < 5; ++st) {
        const int srow = st*16 + l15;
        const bf16x8 a = *(const bf16x8*)(KL + srow*64 + ((f*4 + q) ^ (srow & 7))*8);
        #pragma unroll
        for (int nt = 0; nt < 2; ++nt)
          qk[nt][st] = __builtin_amdgcn_mfma_f32_16x16x32_bf16(a, bq[nt], qk[nt][st], 0, 0, 0);
      }
    }

    #pragma unroll
    for (int nt = 0; nt < 2; ++nt) {
      float mx = -1e30f;
      #pragma unroll
      for (int st = 0; st < 5; ++st)
        #pragma unroll
        for (int r = 0; r < 4; ++r) {
          const int s = st*16 + q*4 + r;
          const float vv = (s < SKV) ? qk[nt][st][r] : -1e30f;
          qk[nt][st][r] = vv;
          mx = fmaxf(mx, vv);
        }
      mx = fmaxf(mx, __shfl_xor(mx, 16));
      mx = fmaxf(mx, __shfl_xor(mx, 32));
      float sum = 0.f;
      #pragma unroll
      for (int st = 0; st < 5; ++st)
        #pragma unroll
        for (int r = 0; r < 4; ++r) {
          const int s = st*16 + q*4 + r;
          const float e = (s < SKV) ? __expf(qk[nt][st][r] - mx) : 0.f;
          qk[nt][st][r] = e;
          sum += e;
        }
      sum += __shfl_xor(sum, 16);
      sum += __shfl_xor(sum, 32);
      const float inv = 1.0f / sum;
      #pragma unroll
      for (int st = 0; st < 5; ++st) {
        s16x4 pv;
        #pragma unroll
        for (int r = 0; r < 4; ++r) pv[r] = f2bf(qk[nt][st][r] * inv);
        *(s16x4*)(scrw + (nt*16 + l15)*104 + st*16 + q*4) = pv;
      }
    }

    f32x4 ov[2][4];
    #pragma unroll
    for (int nt = 0; nt < 2; ++nt)
      #pragma unroll
      for (int dt = 0; dt < 4; ++dt) ov[nt][dt] = z;
    #pragma unroll
    for (int f = 0; f < 3; ++f) {
      bf16x8 bp[2];
      #pragma unroll
      for (int nt = 0; nt < 2; ++nt)
        bp[nt] = *(const bf16x8*)(scrw + (nt*16 + l15)*104 + f*32 + q*8);
      #pragma unroll
      for (int dt = 0; dt < 4; ++dt) {
        const int vrow = dt*16 + l15;
        const bf16x8 a = *(const bf16x8*)(VL + vrow*128 + ((f*4 + q) ^ (vrow & 15))*8);
        #pragma unroll
        for (int nt = 0; nt < 2; ++nt)
          ov[nt][dt] = __builtin_amdgcn_mfma_f32_16x16x32_bf16(a, bp[nt], ov[nt][dt], 0, 0, 0);
      }
    }
    #pragma unroll
    for (int nt = 0; nt < 2; ++nt)
      #pragma unroll
      for (int dt = 0; dt < 4; ++dt) {
        s16x4 pv;
        #pragma unroll
        for (int r = 0; r < 4; ++r) pv[r] = f2bf(ov[nt][dt][r]);
        *(s16x4*)(O_ws + tokrow[nt]*512 + h*64 + dt*16 + q*4) = pv;
      }
  }
}

// ---------------------------------------------------------------------------
// outproj v2: out^T = Wo_t[320][512] @ O_ws^T + bias. BM=160, BN=128, BK=32.
// 2-phase double-buffered staging + XOR-swizzled units. LDS 36,864 B.
// ---------------------------------------------------------------------------
__global__ __launch_bounds__(256) void outproj_kernel(
    const short* __restrict__ O_ws, const short* __restrict__ Wo_t,
    const float* __restrict__ bo, float* __restrict__ out) {
  const int t = threadIdx.x, w = t >> 6, lane = t & 63;
  const int l15 = lane & 15, q = lane >> 4;
  const int c0 = (blockIdx.x & 1) * 160;
  const int t0 = (blockIdx.x >> 1) * 128;
  const int wm = w & 1, wn = w >> 1;

  __shared__ short tile[2][9216];   // per buf: A[160][32] @0, B[128][32] @5120

  auto stage = [&](int it, int bufi) {
    short* buf = tile[bufi];
    const int k0 = it * 32;
    #pragma unroll
    for (int p = 0; p < 5; ++p) {
      const int f = p*256 + t;
      if (f < 1152) {
        const short* g;
        if (f < 640) {
          const int row = f >> 2, c4 = f & 3;
          const int c4s = c4 ^ ((row & 3) ^ ((row >> 2) & 3));
          g = Wo_t + (size_t)(c0 + row)*512 + k0 + c4s*8;
        } else {
          const int f2 = f - 640, row = f2 >> 2, c4 = f2 & 3;
          const int c4s = c4 ^ ((row & 3) ^ ((row >> 2) & 3));
          g = O_ws + (size_t)(t0 + row)*512 + k0 + c4s*8;
        }
        gll16(buf + f*8, g);
      }
    }
  };

  const f32x4 z = {0.f, 0.f, 0.f, 0.f};
  f32x4 acc[5][4];
  #pragma unroll
  for (int mt = 0; mt < 5; ++mt)
    #pragma unroll
    for (int nt = 0; nt < 4; ++nt) acc[mt][nt] = z;

  stage(0, 0);
  __syncthreads();
  const int lperm = (l15 & 3) ^ ((l15 >> 2) & 3);
  for (int it = 0; it < 16; ++it) {
    if (it + 1 < 16) stage(it + 1, (it + 1) & 1);
    const short* buf = tile[it & 1];
    bf16x8 a[5], bb[4];
    #pragma unroll
    for (int mt = 0; mt < 5; ++mt)
      a[mt] = *(const bf16x8*)(buf + (wm*80 + mt*16 + l15)*32 + (q ^ lperm)*8);
    #pragma unroll
    for (int nt = 0; nt < 4; ++nt)
      bb[nt] = *(const bf16x8*)(buf + 5120 + (wn*64 + nt*16 + l15)*32 + (q ^ lperm)*8);
    #pragma unroll
    for (int mt = 0; mt < 5; ++mt)
      #pragma unroll
      for (int nt = 0; nt < 4; ++nt)
        acc[mt][nt] = __builtin_amdgcn_mfma_f32_16x16x32_bf16(a[mt], bb[nt], acc[mt][nt], 0, 0, 0);
    if (it + 1 < 16) __syncthreads();
  }
  const int b = t0 >> 12, n = t0 & 4095;
  #pragma unroll
  for (int mt = 0; mt < 5; ++mt)
    #pragma unroll
    for (int r = 0; r < 4; ++r) {
      const int c = c0 + wm*80 + mt*16 + q*4 + r;
      const float bv = bo[c];
      float* rowp = out + ((size_t)(b*CC + c))*NN + n + wn*64;
      #pragma unroll
      for (int nt = 0; nt < 4; ++nt)
        rowp[nt*16 + l15] = acc[mt][nt][r] + bv;
    }
}

// ---------------------------------------------------------------------------
extern "C" void kernel_launch(void* const* d_in, const int* in_sizes, int n_in,
                              void* d_out, int out_size, void* d_ws, size_t ws_size,
                              hipStream_t stream) {
  const float* query = (const float*)d_in[0];
  const float* kv    = (const float*)d_in[1];
  const float* Wq    = (const float*)d_in[2];
  const float* Wk    = (const float*)d_in[3];
  const float* Wv    = (const float*)d_in[4];
  const float* Wo    = (const float*)d_in[5];
  const float* bo    = (const float*)d_in[6];
  float* out = (float*)d_out;

  char* p = (char*)d_ws;
  short* K_ws  = (short*)(p);             //    819,200 B [8][8][80][64] swz
  short* V_ws  = (short*)(p +   819200);  //  1,048,576 B [8][8][64][128] swz
  short* Wq_t  = (short*)(p +  1867776);  //    327,680 B [512][320] (x SCALE)
  short* Wo_t  = (short*)(p +  2195456);  //    327,680 B [320][512]
  short* kv_bf = (short*)(p +  2523136);  //  1,261,568 B [616][1024]
  short* Wk_t  = (short*)(p +  3784704);  //  1,048,576 B [512][1024]
  short* Wv_t  = (short*)(p +  4833280);  //  1,048,576 B [512][1024]
  short* X_bf  = (short*)(p +  5881856);  // 20,971,520 B [32768][320]
  short* Q_ws  = (short*)(p + 26853376);  // 33,554,432 B [32768][512]
  short* O_ws  = (short*)(p + 60407808);  // 33,554,432 B [32768][512]

  prep_kernel<<<3768, 256, 0, stream>>>(kv, Wk, Wv, Wq, Wo, query, kv_bf,
                                        Wk_t, Wv_t, Wq_t, Wo_t, X_bf,
                                        (unsigned*)V_ws);
  kvproj_kernel<<<dim3(10, 16), 256, 0, stream>>>(kv_bf, Wk_t, Wv_t, K_ws, V_ws);
  qproj_kernel<<<512, 256, 0, stream>>>(X_bf, Wq_t, Q_ws);
  attncore_kernel<<<1024, 256, 0, stream>>>(Q_ws, K_ws, V_ws, O_ws);
  outproj_kernel<<<512, 256, 0, stream>>>(O_ws, Wo_t, bo, out);
}

// Round 9
// 184.114 us; speedup vs baseline: 1.0881x; 1.0067x over previous
//
#include <hip/hip_runtime.h>
#include <hip/hip_bf16.h>
#include <stdint.h>

#define BB     8
#define CC     320
#define NN     4096
#define SKV    77
#define HEADS  8
#define INNER  512
#define SCALE  0.125f

typedef float f32x4  __attribute__((ext_vector_type(4)));
typedef short bf16x8 __attribute__((ext_vector_type(8)));
typedef short s16x4  __attribute__((ext_vector_type(4)));

static __device__ __forceinline__ short f2bf(float f) {
  unsigned u = __float_as_uint(f);
  return (short)((u + 0x7fffu + ((u >> 16) & 1u)) >> 16);
}

// async global->LDS 16B copy; LDS dest is wave-uniform base + lane*16.
static __device__ __forceinline__ void gll16(void* lds, const void* g) {
  auto gp = reinterpret_cast<const uint32_t __attribute__((address_space(1)))*>(
      reinterpret_cast<uintptr_t>(g));
  auto lp = reinterpret_cast<uint32_t __attribute__((address_space(3)))*>(
      reinterpret_cast<uintptr_t>(lds));
  __builtin_amdgcn_global_load_lds(gp, lp, 16, 0, 0);
}

// ---------------------------------------------------------------------------
// prep: kv->bf16 | Wk,Wv,Wq(x SCALE),Wo transposes | zero V_ws.
// blocks: [0,616) kv | [616,872) Wk/Wv | [872,912) Wq | [912,952) Wo |
// [952,1208) zero V_ws (1 MB). NO query xpose (done in proj kernel).
// ---------------------------------------------------------------------------
__global__ __launch_bounds__(256) void prep_kernel(
    const float* __restrict__ kv, const float* __restrict__ Wk,
    const float* __restrict__ Wv, const float* __restrict__ Wq,
    const float* __restrict__ Wo, short* __restrict__ kv_bf,
    short* __restrict__ Wk_t, short* __restrict__ Wv_t,
    short* __restrict__ Wq_t, short* __restrict__ Wo_t,
    unsigned* __restrict__ zero_base) {
  __shared__ float T[64 * 65];
  const int blk = blockIdx.x, t = threadIdx.x;
  if (blk < 616) {
    const int base = blk * 1024;
    #pragma unroll
    for (int i = 0; i < 4; ++i) kv_bf[base + i*256 + t] = f2bf(kv[base + i*256 + t]);
    return;
  }
  if (blk >= 952) {               // zero V_ws (pad cols read by PV must be 0)
    const int base = (blk - 952) * 1024;
    #pragma unroll
    for (int i = 0; i < 4; ++i) zero_base[base + i*256 + t] = 0u;
    return;
  }
  const float* src; short* dst; int RS, CS, kt, ct; float scl = 1.0f;
  if (blk < 872) {               // Wk/Wv: [1024][512] -> [512][1024]
    const int tile = blk - 616;
    const bool isK = tile < 128;
    const int tt = isK ? tile : tile - 128;
    src = isK ? Wk : Wv; dst = isK ? Wk_t : Wv_t;
    RS = 1024; CS = 512; kt = tt >> 3; ct = tt & 7;
  } else if (blk < 912) {        // Wq: [320][512] -> [512][320], x SCALE
    const int tt = blk - 872;
    src = Wq; dst = Wq_t; RS = 320; CS = 512; kt = tt >> 3; ct = tt & 7;
    scl = SCALE;
  } else {                       // Wo: [512][320] -> [320][512]
    const int tt = blk - 912;
    src = Wo; dst = Wo_t; RS = 512; CS = 320; kt = tt / 5; ct = tt % 5;
  }
  const int cl = t & 63, rb = t >> 6;
  #pragma unroll
  for (int i = 0; i < 16; ++i)
    T[(rb + i*4)*65 + cl] = src[(size_t)(kt*64 + rb + i*4)*CS + ct*64 + cl];
  __syncthreads();
  #pragma unroll
  for (int i = 0; i < 16; ++i) {
    const int nl = rb + i*4;
    dst[(size_t)(ct*64 + nl)*RS + kt*64 + cl] = f2bf(T[cl*65 + nl] * scl);
  }
}

// ---------------------------------------------------------------------------
// proj: qproj + kvproj merged by block range (independent work, one launch).
// blocks [0,1024): qproj. block = 64 tok x 256 j (j0 = (blk&1)*256).
//   Phase 0: query fp32 -> A[64][328] bf16 in-LDS transpose (no X_bf).
//   K-loop: Wq_t staged 2-phase dbuf via gll16, XOR-swizzled units.
//   LDS 74,752 B -> 2 blocks/CU.
// blocks [1024,1344): kvproj. 10 m-tiles x 32 (isK, h, dhalf) units; per
//   wave 16 rows x 32 cols, 32 K-steps. 2x blocks of round-8 (latency /2).
//   K_ws [b][h][80][64] swz (u ^= s&7); V_ws [b][h][64][128] swz (u ^= d&15).
// ---------------------------------------------------------------------------
__global__ __launch_bounds__(256, 2) void proj_kernel(
    const float* __restrict__ query, const short* __restrict__ Wq_t,
    const short* __restrict__ kv_bf, const short* __restrict__ Wk_t,
    const short* __restrict__ Wv_t, short* __restrict__ Q_ws,
    short* __restrict__ K_ws, short* __restrict__ V_ws) {
  const int t = threadIdx.x, w = t >> 6, lane = t & 63;
  const int l15 = lane & 15, q = lane >> 4;

  __shared__ short A[64 * 328];      // 41,984 B
  __shared__ short Bt[2][8192];      // 32,768 B

  if (blockIdx.x >= 1024) {          // ---------------- kvproj ----------------
    const int blk2 = blockIdx.x - 1024;
    const int bx = blk2 % 10;
    const int y  = blk2 / 10;        // 0..31
    const bool isK = (y < 16);
    const int yy = isK ? y : y - 16;
    const int h = yy >> 1, dh = yy & 1;
    const short* __restrict__ Wt = isK ? Wk_t : Wv_t;
    const int m0 = (bx * 4 + w) * 16;
    const int arow = (m0 + l15 < 616) ? (m0 + l15) : 615;

    const f32x4 z = {0.f, 0.f, 0.f, 0.f};
    f32x4 acc[2] = {z, z};
    for (int k0 = 0; k0 < 1024; k0 += 32) {
      const bf16x8 a = *(const bf16x8*)(kv_bf + (size_t)arow*1024 + k0 + q*8);
      #pragma unroll
      for (int nt = 0; nt < 2; ++nt) {
        const int n = h*64 + dh*32 + nt*16 + l15;
        const bf16x8 bfr = *(const bf16x8*)(Wt + (size_t)n*1024 + k0 + q*8);
        acc[nt] = __builtin_amdgcn_mfma_f32_16x16x32_bf16(a, bfr, acc[nt], 0, 0, 0);
      }
    }
    #pragma unroll
    for (int nt = 0; nt < 2; ++nt) {
      const int d = dh*32 + nt*16 + l15;
      #pragma unroll
      for (int r = 0; r < 4; ++r) {
        const int row = m0 + q*4 + r;
        if (row < 616) {
          const int b = (int)(((unsigned)row * 54472u) >> 22);   // row/77
          const int s = row - b*77;
          if (isK) {
            const int u = (d >> 3) ^ (s & 7);
            K_ws[(size_t)((b*8 + h)*80 + s)*64 + u*8 + (d & 7)] = f2bf(acc[nt][r]);
          } else {
            const int u = (s >> 3) ^ (d & 15);
            V_ws[(size_t)((b*8 + h)*64 + d)*128 + u*8 + (s & 7)] = f2bf(acc[nt][r]);
          }
        }
      }
    }
    return;
  }

  // ---------------- qproj ----------------
  const int g = blockIdx.x >> 1;         // 512 token-tiles
  const int b = g >> 6;
  const int n0 = (g & 63) * 64;
  const int j0 = (blockIdx.x & 1) * 256;
  const int wm = w & 1, wn = w >> 1;

  // phase 0: query -> A[tok][c]
  {
    const float* qb = query + (size_t)b * CC * NN + n0;
    #pragma unroll
    for (int i = 0; i < 20; ++i) {
      const int f = i * 256 + t;
      const int c = f >> 4, n4 = (f & 15) * 4;
      const f32x4 v = *(const f32x4*)(qb + (size_t)c * NN + n4);
      #pragma unroll
      for (int j = 0; j < 4; ++j)
        A[(n4 + j) * 328 + c] = f2bf(v[j]);
    }
  }

  auto stage = [&](int it, int bufi) {   // 256 rows x 32k = 1024 slots
    short* buf = Bt[bufi];
    const int k0 = it * 32;
    #pragma unroll
    for (int p = 0; p < 4; ++p) {
      const int f = p*256 + t, row = f >> 2, c4 = f & 3;
      const int c4s = c4 ^ ((row & 3) ^ ((row >> 2) & 3));
      gll16(buf + f*8, Wq_t + (size_t)(j0 + row)*320 + k0 + c4s*8);
    }
  };

  const f32x4 z = {0.f, 0.f, 0.f, 0.f};
  f32x4 acc[2][8];
  #pragma unroll
  for (int mt = 0; mt < 2; ++mt)
    #pragma unroll
    for (int nt = 0; nt < 8; ++nt) acc[mt][nt] = z;

  stage(0, 0);
  __syncthreads();                       // A-panel + buf0 ready
  const int lperm = (l15 & 3) ^ ((l15 >> 2) & 3);
  for (int it = 0; it < 10; ++it) {
    if (it + 1 < 10) stage(it + 1, (it + 1) & 1);   // in flight over compute
    const short* buf = Bt[it & 1];
    const int k0 = it * 32;
    bf16x8 a[2], bb[8];
    #pragma unroll
    for (int mt = 0; mt < 2; ++mt)
      a[mt] = *(const bf16x8*)(A + (wm*32 + mt*16 + l15)*328 + k0 + q*8);
    #pragma unroll
    for (int nt = 0; nt < 8; ++nt)
      bb[nt] = *(const bf16x8*)(buf + ((wn*128 + nt*16 + l15)*4 + (q ^ lperm))*8);
    #pragma unroll
    for (int mt = 0; mt < 2; ++mt)
      #pragma unroll
      for (int nt = 0; nt < 8; ++nt)
        acc[mt][nt] = __builtin_amdgcn_mfma_f32_16x16x32_bf16(a[mt], bb[nt], acc[mt][nt], 0, 0, 0);
    if (it + 1 < 10) __syncthreads();    // drains stage(it+1)
  }
  #pragma unroll
  for (int mt = 0; mt < 2; ++mt)
    #pragma unroll
    for (int r = 0; r < 4; ++r) {
      short* rowp = Q_ws + (size_t)(b*NN + n0 + wm*32 + mt*16 + q*4 + r)*512 + j0 + wn*128;
      #pragma unroll
      for (int nt = 0; nt < 8; ++nt)
        rowp[nt*16 + l15] = f2bf(acc[mt][nt][r]);
    }
}

// ---------------------------------------------------------------------------
// attncore v2 (round-8, unchanged): block = (b, h, 256 tokens); 4 waves x
// 64 tok. K/V staged once per block via linear gll16 (global pre-swizzled)
// -> conflict-free ds_read, zero K/V gathers. grid 1024, LDS 53,248 B.
// ---------------------------------------------------------------------------
__global__ __launch_bounds__(256) void attncore_kernel(
    const short* __restrict__ Q_ws, const short* __restrict__ K_ws,
    const short* __restrict__ V_ws, short* __restrict__ O_ws) {
  const int t = threadIdx.x, w = t >> 6, lane = t & 63;
  const int l15 = lane & 15, q = lane >> 4;
  const int b = blockIdx.x >> 7;
  const int r7 = blockIdx.x & 127;
  const int h = r7 >> 4;
  const int rng = r7 & 15;

  __shared__ short KL[80 * 64];        // swizzled units (u ^ (s&7))
  __shared__ short VL[64 * 128];       // swizzled units (u ^ (d&15))
  __shared__ short scr[4 * 32 * 104];  // per-wave P

  const short* __restrict__ Kg = K_ws + (size_t)(b*8 + h) * 80 * 64;
  const short* __restrict__ Vg = V_ws + (size_t)(b*8 + h) * 64 * 128;
  #pragma unroll
  for (int p = 0; p < 3; ++p) {
    const int L = p*256 + t;
    if (L < 640) gll16(KL + L*8, Kg + L*8);
  }
  #pragma unroll
  for (int p = 0; p < 4; ++p) {
    const int L = p*256 + t;
    gll16(VL + L*8, Vg + L*8);
  }
  short* scrw = scr + w * 3328;
  for (int i = lane; i < 1664; i += 64) ((unsigned*)scrw)[i] = 0u;
  __syncthreads();                     // K/V staged (implicit vmcnt drain)

  const f32x4 z = {0.f, 0.f, 0.f, 0.f};
  for (int chunk = 0; chunk < 2; ++chunk) {
    const int n0 = rng * 256 + w * 64 + chunk * 32;
    size_t tokrow[2];
    #pragma unroll
    for (int nt = 0; nt < 2; ++nt) tokrow[nt] = (size_t)(b*NN + n0 + nt*16 + l15);

    f32x4 qk[2][5];
    #pragma unroll
    for (int nt = 0; nt < 2; ++nt)
      #pragma unroll
      for (int st = 0; st < 5; ++st) qk[nt][st] = z;
    #pragma unroll
    for (int f = 0; f < 2; ++f) {
      bf16x8 bq[2];
      #pragma unroll
      for (int nt = 0; nt < 2; ++nt)
        bq[nt] = *(const bf16x8*)(Q_ws + tokrow[nt]*512 + h*64 + f*32 + q*8);
      #pragma unroll
      for (int st = 0; st < 5; ++st) {
        const int srow = st*16 + l15;
        const bf16x8 a = *(const bf16x8*)(KL + srow*64 + ((f*4 + q) ^ (srow & 7))*8);
        #pragma unroll
        for (int nt = 0; nt < 2; ++nt)
          qk[nt][st] = __builtin_amdgcn_mfma_f32_16x16x32_bf16(a, bq[nt], qk[nt][st], 0, 0, 0);
      }
    }

    #pragma unroll
    for (int nt = 0; nt < 2; ++nt) {
      float mx = -1e30f;
      #pragma unroll
      for (int st = 0; st < 5; ++st)
        #pragma unroll
        for (int r = 0; r < 4; ++r) {
          const int s = st*16 + q*4 + r;
          const float vv = (s < SKV) ? qk[nt][st][r] : -1e30f;
          qk[nt][st][r] = vv;
          mx = fmaxf(mx, vv);
        }
      mx = fmaxf(mx, __shfl_xor(mx, 16));
      mx = fmaxf(mx, __shfl_xor(mx, 32));
      float sum = 0.f;
      #pragma unroll
      for (int st = 0; st < 5; ++st)
        #pragma unroll
        for (int r = 0; r < 4; ++r) {
          const int s = st*16 + q*4 + r;
          const float e = (s < SKV) ? __expf(qk[nt][st][r] - mx) : 0.f;
          qk[nt][st][r] = e;
          sum += e;
        }
      sum += __shfl_xor(sum, 16);
      sum += __shfl_xor(sum, 32);
      const float inv = 1.0f / sum;
      #pragma unroll
      for (int st = 0; st < 5; ++st) {
        s16x4 pv;
        #pragma unroll
        for (int r = 0; r < 4; ++r) pv[r] = f2bf(qk[nt][st][r] * inv);
        *(s16x4*)(scrw + (nt*16 + l15)*104 + st*16 + q*4) = pv;
      }
    }

    f32x4 ov[2][4];
    #pragma unroll
    for (int nt = 0; nt < 2; ++nt)
      #pragma unroll
      for (int dt = 0; dt < 4; ++dt) ov[nt][dt] = z;
    #pragma unroll
    for (int f = 0; f < 3; ++f) {
      bf16x8 bp[2];
      #pragma unroll
      for (int nt = 0; nt < 2; ++nt)
        bp[nt] = *(const bf16x8*)(scrw + (nt*16 + l15)*104 + f*32 + q*8);
      #pragma unroll
      for (int dt = 0; dt < 4; ++dt) {
        const int vrow = dt*16 + l15;
        const bf16x8 a = *(const bf16x8*)(VL + vrow*128 + ((f*4 + q) ^ (vrow & 15))*8);
        #pragma unroll
        for (int nt = 0; nt < 2; ++nt)
          ov[nt][dt] = __builtin_amdgcn_mfma_f32_16x16x32_bf16(a, bp[nt], ov[nt][dt], 0, 0, 0);
      }
    }
    #pragma unroll
    for (int nt = 0; nt < 2; ++nt)
      #pragma unroll
      for (int dt = 0; dt < 4; ++dt) {
        s16x4 pv;
        #pragma unroll
        for (int r = 0; r < 4; ++r) pv[r] = f2bf(ov[nt][dt][r]);
        *(s16x4*)(O_ws + tokrow[nt]*512 + h*64 + dt*16 + q*4) = pv;
      }
  }
}

// ---------------------------------------------------------------------------
// outproj v2 (round-8, unchanged): out^T = Wo_t @ O_ws^T + bias.
// BM=160, BN=128, BK=32; 2-phase dbuf + XOR-swizzled units. LDS 36,864 B.
// ---------------------------------------------------------------------------
__global__ __launch_bounds__(256) void outproj_kernel(
    const short* __restrict__ O_ws, const short* __restrict__ Wo_t,
    const float* __restrict__ bo, float* __restrict__ out) {
  const int t = threadIdx.x, w = t >> 6, lane = t & 63;
  const int l15 = lane & 15, q = lane >> 4;
  const int c0 = (blockIdx.x & 1) * 160;
  const int t0 = (blockIdx.x >> 1) * 128;
  const int wm = w & 1, wn = w >> 1;

  __shared__ short tile[2][9216];   // per buf: A[160][32] @0, B[128][32] @5120

  auto stage = [&](int it, int bufi) {
    short* buf = tile[bufi];
    const int k0 = it * 32;
    #pragma unroll
    for (int p = 0; p < 5; ++p) {
      const int f = p*256 + t;
      if (f < 1152) {
        const short* g;
        if (f < 640) {
          const int row = f >> 2, c4 = f & 3;
          const int c4s = c4 ^ ((row & 3) ^ ((row >> 2) & 3));
          g = Wo_t + (size_t)(c0 + row)*512 + k0 + c4s*8;
        } else {
          const int f2 = f - 640, row = f2 >> 2, c4 = f2 & 3;
          const int c4s = c4 ^ ((row & 3) ^ ((row >> 2) & 3));
          g = O_ws + (size_t)(t0 + row)*512 + k0 + c4s*8;
        }
        gll16(buf + f*8, g);
      }
    }
  };

  const f32x4 z = {0.f, 0.f, 0.f, 0.f};
  f32x4 acc[5][4];
  #pragma unroll
  for (int mt = 0; mt < 5; ++mt)
    #pragma unroll
    for (int nt = 0; nt < 4; ++nt) acc[mt][nt] = z;

  stage(0, 0);
  __syncthreads();
  const int lperm = (l15 & 3) ^ ((l15 >> 2) & 3);
  for (int it = 0; it < 16; ++it) {
    if (it + 1 < 16) stage(it + 1, (it + 1) & 1);
    const short* buf = tile[it & 1];
    bf16x8 a[5], bb[4];
    #pragma unroll
    for (int mt = 0; mt < 5; ++mt)
      a[mt] = *(const bf16x8*)(buf + ((wm*80 + mt*16 + l15)*4 + (q ^ lperm))*8);
    #pragma unroll
    for (int nt = 0; nt < 4; ++nt)
      bb[nt] = *(const bf16x8*)(buf + 5120 + ((wn*64 + nt*16 + l15)*4 + (q ^ lperm))*8);
    #pragma unroll
    for (int mt = 0; mt < 5; ++mt)
      #pragma unroll
      for (int nt = 0; nt < 4; ++nt)
        acc[mt][nt] = __builtin_amdgcn_mfma_f32_16x16x32_bf16(a[mt], bb[nt], acc[mt][nt], 0, 0, 0);
    if (it + 1 < 16) __syncthreads();
  }
  const int b = t0 >> 12, n = t0 & 4095;
  #pragma unroll
  for (int mt = 0; mt < 5; ++mt)
    #pragma unroll
    for (int r = 0; r < 4; ++r) {
      const int c = c0 + wm*80 + mt*16 + q*4 + r;
      const float bv = bo[c];
      float* rowp = out + ((size_t)(b*CC + c))*NN + n + wn*64;
      #pragma unroll
      for (int nt = 0; nt < 4; ++nt)
        rowp[nt*16 + l15] = acc[mt][nt][r] + bv;
    }
}

// ---------------------------------------------------------------------------
extern "C" void kernel_launch(void* const* d_in, const int* in_sizes, int n_in,
                              void* d_out, int out_size, void* d_ws, size_t ws_size,
                              hipStream_t stream) {
  const float* query = (const float*)d_in[0];
  const float* kv    = (const float*)d_in[1];
  const float* Wq    = (const float*)d_in[2];
  const float* Wk    = (const float*)d_in[3];
  const float* Wv    = (const float*)d_in[4];
  const float* Wo    = (const float*)d_in[5];
  const float* bo    = (const float*)d_in[6];
  float* out = (float*)d_out;

  char* p = (char*)d_ws;
  short* K_ws  = (short*)(p);             //    819,200 B [8][8][80][64] swz
  short* V_ws  = (short*)(p +   819200);  //  1,048,576 B [8][8][64][128] swz
  short* Wq_t  = (short*)(p +  1867776);  //    327,680 B [512][320] (x SCALE)
  short* Wo_t  = (short*)(p +  2195456);  //    327,680 B [320][512]
  short* kv_bf = (short*)(p +  2523136);  //  1,261,568 B [616][1024]
  short* Wk_t  = (short*)(p +  3784704);  //  1,048,576 B [512][1024]
  short* Wv_t  = (short*)(p +  4833280);  //  1,048,576 B [512][1024]
  short* Q_ws  = (short*)(p +  5881856);  // 33,554,432 B [32768][512]
  short* O_ws  = (short*)(p + 39436288);  // 33,554,432 B [32768][512]

  prep_kernel<<<1208, 256, 0, stream>>>(kv, Wk, Wv, Wq, Wo, kv_bf,
                                        Wk_t, Wv_t, Wq_t, Wo_t,
                                        (unsigned*)V_ws);
  proj_kernel<<<1344, 256, 0, stream>>>(query, Wq_t, kv_bf, Wk_t, Wv_t,
                                        Q_ws, K_ws, V_ws);
  attncore_kernel<<<1024, 256, 0, stream>>>(Q_ws, K_ws, V_ws, O_ws);
  outproj_kernel<<<512, 256, 0, stream>>>(O_ws, Wo_t, bo, out);
}